// Round 1
// baseline (167.319 us; speedup 1.0000x reference)
//
#include <hip/hip_runtime.h>
#include <hip/hip_bf16.h>

// GruDirection3d forward, d1=d2=d3=1.
// out[b,c,d,y,x] = z*h_tilde + (1-z)*out[b,c,d-1,y-1,x-1], border = h0.
// Decomposes into independent diagonal chains. One thread per chain.
// B=2, C=96, D=H=W=32. Chains per (b,c): 32^3 - 31^3 = 2977.

#define D_ 32
#define H_ 32
#define W_ 32
#define NCHAIN 2977   // 1024 (d0=0 face) + 992 (y0=0, d0>=1) + 961 (x0=0, d0>=1, y0>=1)

__global__ __launch_bounds__(256) void gru3d_chains(
    const float* __restrict__ z,
    const float* __restrict__ ht,
    const float* __restrict__ h0p,
    float* __restrict__ out)
{
    const int bc  = blockIdx.y;                       // 0..191 (b*C+c)
    const int cid = blockIdx.x * blockDim.x + threadIdx.x;
    if (cid >= NCHAIN) return;

    // Decode chain start (d0, y0, x0) with min(d0,y0,x0) == 0.
    int d0, y0, x0;
    if (cid < 1024) {                 // d0 == 0 face: 32*32 chains
        d0 = 0; y0 = cid >> 5; x0 = cid & 31;
    } else if (cid < 2016) {          // y0 == 0, d0 in 1..31: 31*32 chains
        int r = cid - 1024;
        d0 = 1 + (r >> 5); y0 = 0; x0 = r & 31;
    } else {                          // x0 == 0, d0,y0 in 1..31: 31*31 chains
        int r = cid - 2016;
        d0 = 1 + r / 31; y0 = 1 + r % 31; x0 = 0;
    }

    int m   = max(d0, max(y0, x0));
    int len = D_ - m;                 // chain length (1..32)

    float h = h0p[0];
    int idx = bc * (D_ * H_ * W_) + (d0 * H_ + y0) * W_ + x0;
    const int stride = H_ * W_ + W_ + 1;   // (+1,+1,+1) diagonal step

    for (int t = 0; t < len; ++t) {
        float zv = z[idx];
        float hv = ht[idx];
        h = zv * hv + (1.0f - zv) * h;     // matches reference arithmetic
        out[idx] = h;
        idx += stride;
    }
}

extern "C" void kernel_launch(void* const* d_in, const int* in_sizes, int n_in,
                              void* d_out, int out_size, void* d_ws, size_t ws_size,
                              hipStream_t stream) {
    const float* z  = (const float*)d_in[0];
    const float* ht = (const float*)d_in[1];
    const float* h0 = (const float*)d_in[2];
    float* out      = (float*)d_out;

    const int BC = 2 * 96;                 // B*C = 192 slabs
    dim3 block(256);
    dim3 grid((NCHAIN + 255) / 256, BC);   // 12 x 192 blocks
    gru3d_chains<<<grid, block, 0, stream>>>(z, ht, h0, out);
}

// Round 2
// 99.765 us; speedup vs baseline: 1.6771x; 1.6771x over previous
//
#include <hip/hip_runtime.h>
#include <hip/hip_bf16.h>

// GruDirection3d forward, d1=d2=d3=1. B=2, C=96, D=H=W=32.
// out[b,c,d,y,x] = z*h_tilde + (1-z)*out[b,c,d-1,y-1,x-1], border = h0.
//
// Plane-wavefront DP: one 1024-thread block per (b,c) slab; thread (y,x)
// computes one element of each d-plane. The d-1 plane is kept in
// double-buffered LDS (shifted read at (y-1,x-1) => tid-33, stride-1 across
// lanes -> conflict-free). Global loads are perfectly coalesced 4KB planes,
// prefetched one step ahead into registers.

#define PLANE 1024              // 32*32
#define DD 32

__global__ __launch_bounds__(1024) void gru3d_wavefront(
    const float* __restrict__ z,
    const float* __restrict__ ht,
    const float* __restrict__ h0p,
    float* __restrict__ out)
{
    __shared__ float buf[2][PLANE];

    const int bc  = blockIdx.x;           // 0..191
    const int tid = threadIdx.x;          // y*32 + x
    const int y   = tid >> 5;
    const int x   = tid & 31;
    const float h0 = h0p[0];

    const float* zb = z   + (size_t)bc * (DD * PLANE);
    const float* tb = ht  + (size_t)bc * (DD * PLANE);
    float*       ob = out + (size_t)bc * (DD * PLANE);

    // Prefetch planes d=0 and d=1.
    float zA = zb[tid];
    float tA = tb[tid];
    float zB = zb[PLANE + tid];
    float tB = tb[PLANE + tid];

    // d = 0: predecessor is the h0 border everywhere.
    float h = zA * tA + (1.0f - zA) * h0;
    ob[tid] = h;
    buf[0][tid] = h;
    __syncthreads();

    const bool interior = (y > 0) & (x > 0);

    #pragma unroll 4
    for (int d = 1; d < DD; ++d) {
        zA = zB; tA = tB;
        if (d + 1 < DD) {                 // prefetch plane d+1
            zB = zb[(d + 1) * PLANE + tid];
            tB = tb[(d + 1) * PLANE + tid];
        }
        float pv = interior ? buf[(d - 1) & 1][tid - 33] : h0;
        float hn = zA * tA + (1.0f - zA) * pv;
        ob[d * PLANE + tid] = hn;
        buf[d & 1][tid] = hn;
        __syncthreads();
    }
}

extern "C" void kernel_launch(void* const* d_in, const int* in_sizes, int n_in,
                              void* d_out, int out_size, void* d_ws, size_t ws_size,
                              hipStream_t stream) {
    const float* z  = (const float*)d_in[0];
    const float* ht = (const float*)d_in[1];
    const float* h0 = (const float*)d_in[2];
    float* out      = (float*)d_out;

    const int BC = 2 * 96;                // 192 slabs, one block each
    gru3d_wavefront<<<dim3(BC), dim3(1024), 0, stream>>>(z, ht, h0, out);
}